// Round 6
// baseline (351.360 us; speedup 1.0000x reference)
//
#include <hip/hip_runtime.h>

// ResFCEventuallyLayer — (1) fused fp32->bf16 pre-convert into d_ws,
// (2) 256x128-tile dbuf bf16 MFMA GEMM (multi-block TLP) + fused epilogue.
//   rs   = x @ W^T            (einsum "bj,ij->bi": both operands K-major)
//   out1 = relu(1 - beta + rs)
//   res  = relu(1 - (beta_res - (x + out1)));  LeakyReLU(res>=0) == identity
//
// R12: abandon 1-block/CU intra-block scheduling (3 failed variants, all
// 163-171us: barriers sync the whole CU -> LDS crunch and MFMA serialize).
// New mechanism: cross-block TLP (m97/m114) with 256^2-grade wave tiles.
//   BM=256 BN=128 BK=32, 4 waves (2Mx2N), wave-tile 128x64 (same LDS-read
//   per output as the 256^2 kernel), LDS 48KB -> 2 blocks/CU, grid 512 =
//   exactly 2/CU. One __syncthreads per K-tile: its implicit
//   vmcnt(0)+lgkmcnt(0) drain is the RAW fence for the DMA prefetch; the
//   previous barrier is the WAR fence (dbuf). Proven sub-patterns only:
//   global_load_lds linear-dest + inverse-swizzled source (rule 21),
//   st_16x32 subtile swizzle (0 conflicts, R3-R5 measured), C/D layout.

#define NDIM 4096

typedef __bf16 bf16x8 __attribute__((ext_vector_type(8)));
typedef float f32x4 __attribute__((ext_vector_type(4)));

__device__ unsigned short f2bf(float f) {
    unsigned int x;
    __builtin_memcpy(&x, &f, 4);
    unsigned int r = x + 0x7FFFu + ((x >> 16) & 1u);   // round-to-nearest-even
    return (unsigned short)(r >> 16);
}

__device__ unsigned int pack_bf2(float lo, float hi) {
    return (unsigned int)f2bf(lo) | ((unsigned int)f2bf(hi) << 16);
}

// Direct global->LDS DMA, 16 B per lane: wave-uniform LDS base + lane*16.
__device__ inline void gload16(const uint4* g, unsigned int* l) {
    __builtin_amdgcn_global_load_lds(
        (const __attribute__((address_space(1))) unsigned int*)g,
        (__attribute__((address_space(3))) unsigned int*)l,
        16, 0, 0);
}

// Phase 1 (fused): fp32 -> packed bf16 for BOTH X and W in one launch.
__global__ void convert_f32_bf16_kernel(const float* X, unsigned int* Xbf,
                                        const float* W, unsigned int* Wbf) {
    unsigned int bid = blockIdx.x;
    const float* src;
    unsigned int* dst;
    if (bid < 8192) { src = X; dst = Xbf; }
    else            { src = W; dst = Wbf; bid -= 8192; }
    const size_t i = ((size_t)bid * blockDim.x + threadIdx.x) * 8;
    float4 v0 = *(const float4*)(src + i);
    float4 v1 = *(const float4*)(src + i + 4);
    uint4 u;
    u.x = pack_bf2(v0.x, v0.y);
    u.y = pack_bf2(v0.z, v0.w);
    u.z = pack_bf2(v1.x, v1.y);
    u.w = pack_bf2(v1.z, v1.w);
    *(uint4*)(dst + i / 2) = u;
}

// Stage one K-tile (A: 16KB = 4 rounds, B: 8KB = 2 rounds; 6 loads/thread).
#define STAGE(buf, S) do { \
    gload16(Ab4 + offA[0] + (S) * 4, &sAU[buf][0 * 1024 + wq]); \
    gload16(Ab4 + offA[1] + (S) * 4, &sAU[buf][1 * 1024 + wq]); \
    gload16(Ab4 + offA[2] + (S) * 4, &sAU[buf][2 * 1024 + wq]); \
    gload16(Ab4 + offA[3] + (S) * 4, &sAU[buf][3 * 1024 + wq]); \
    gload16(Bb4 + offB[0] + (S) * 4, &sBU[buf][0 * 1024 + wq]); \
    gload16(Bb4 + offB[1] + (S) * 4, &sBU[buf][1 * 1024 + wq]); \
} while (0)

// Read frags (8+4 ds_read_b128) + 32 independent MFMAs for one K-tile.
#define COMPUTE(b) do { \
    bf16x8 af[8], bfr[4]; \
    _Pragma("unroll") for (int _m = 0; _m < 8; _m++) \
        af[_m] = ((const bf16x8*)sAU[b])[afB + _m * 64]; \
    _Pragma("unroll") for (int _n = 0; _n < 4; _n++) \
        bfr[_n] = ((const bf16x8*)sBU[b])[bfB + _n * 64]; \
    _Pragma("unroll") for (int _m = 0; _m < 8; _m++) \
    _Pragma("unroll") for (int _n = 0; _n < 4; _n++) \
        acc[_m][_n] = __builtin_amdgcn_mfma_f32_16x16x32_bf16( \
            af[_m], bfr[_n], acc[_m][_n], 0, 0, 0); \
} while (0)

// Phase 2: 256x128 tile, BK=32, 4 waves (2Mx2N), dbuf, 2 blocks/CU.
__global__ void __launch_bounds__(256, 2)
ResFCEventuallyLayer_82205674045459_kernel(
    const unsigned int* Xbf, const unsigned int* Wbf,
    const float* X, const float* Bp, const float* Br,
    float* out)
{
    // A buf: 256 rows x 32 k x bf16 = 16KB = 16 subtiles x 1KB.
    // B buf: 128 rows x 32 k = 8KB = 8 subtiles. Subtile = 16 rows x 64B;
    // within: byte ^= ((byte>>9)&1)<<5  (16B chunk c ^= ((r>>3)&1)<<1).
    __shared__ __align__(16) unsigned int sAU[2][4096];
    __shared__ __align__(16) unsigned int sBU[2][2048];

    const int t    = threadIdx.x;      // 0..255
    const int lane = t & 63;
    const int wave = t >> 6;           // 0..3
    const int quad = lane >> 4;        // 0..3
    const int l16  = lane & 15;
    const int wm   = wave >> 1;        // 0..1: 128-row half
    const int wn   = wave & 1;         // 0..1: 64-col half
    const int wq   = wave * 256;       // uint offset of wave's 1KB DMA slice

    // Grid 512 (= 2/CU exactly); bijective XCD swizzle (512 % 8 == 0).
    const int bid = blockIdx.x;
    const int swz = ((bid & 7) << 6) | (bid >> 3);      // xcd*64 + local
    const int bm0 = (swz >> 5) * 256;                   // 16 M-tiles
    const int bn0 = (swz & 31) * 128;                   // 32 N-tiles

    const uint4* Ab4 = (const uint4*)Xbf;   // 512 uint4 per global row
    const uint4* Bb4 = (const uint4*)Wbf;

    // Inverse-swizzle the global source for the linear-dest DMA (rule 21):
    // phys chunk p = rr*256 + t -> row = p>>2, logical k-chunk
    // cl = (p&3) ^ ((row&15)>>3)<<1.
    int offA[4], offB[2];
#pragma unroll
    for (int rr = 0; rr < 4; rr++) {
        const int p  = rr * 256 + t;
        const int cl = (p & 3) ^ ((((p >> 2) & 15) >> 3) << 1);
        offA[rr] = (bm0 + (p >> 2)) * 512 + cl;
    }
#pragma unroll
    for (int rr = 0; rr < 2; rr++) {
        const int p  = rr * 256 + t;
        const int cl = (p & 3) ^ ((((p >> 2) & 15) >> 3) << 1);
        offB[rr] = (bn0 + (p >> 2)) * 512 + cl;
    }

    // Fragment addressing (matches staged swizzle); conflict-free:
    // byte = subtile*1024 + l16*64 + (quad*16 ^ ((l16>>3)<<5)).
    const int laneByte = l16 * 64 + ((quad * 16) ^ (((l16 >> 3) & 1) << 5));
    const int afB = (wm * 8192 + laneByte) >> 4;    // bf16x8 units
    const int bfB = (wn * 4096 + laneByte) >> 4;

    f32x4 acc[8][4];
#pragma unroll
    for (int i = 0; i < 8; i++)
#pragma unroll
        for (int j = 0; j < 4; j++)
#pragma unroll
            for (int r = 0; r < 4; r++)
                acc[i][j][r] = 0.0f;

    // Prologue: tile 0 into buf0; syncthreads drains the DMA (vmcnt 0).
    STAGE(0, 0);
    __syncthreads();

    // 128 K-tiles, 2 per iteration. One __syncthreads per K-tile:
    //   WAR: prefetch target's reads finished before previous barrier.
    //   RAW: barrier's implicit vmcnt(0) drains the prefetch.
    for (int s = 0; s < 128; s += 2) {
        STAGE(1, s + 1);                   // prefetch odd tile -> buf1
        COMPUTE(0);
        __syncthreads();
        STAGE(0, (s + 2) & 127);           // prefetch next even -> buf0
                                           // (wraps harmlessly on last iter)
        COMPUTE(1);
        __syncthreads();
    }

    // Fused epilogue. C/D layout: n(col) = lane&15, m(row) = quad*4 + reg.
    const float one_m_beta = 1.0f - Bp[0];
#pragma unroll
    for (int nt = 0; nt < 4; nt++) {
        const int n = bn0 + wn * 64 + nt * 16 + l16;
        const float br = Br[n];
#pragma unroll
        for (int mt = 0; mt < 8; mt++) {
            const int mbase = bm0 + wm * 128 + mt * 16 + quad * 4;
#pragma unroll
            for (int r = 0; r < 4; r++) {
                const size_t idx = (size_t)(mbase + r) * NDIM + n;
                float v = acc[mt][nt][r] + one_m_beta;
                if (v < 0.0f) v = 0.0f;                 // relu(1 - beta + rowsum)
                float res = 1.0f - br + X[idx] + v;
                if (res < 0.0f) res = 0.0f;             // relu; leaky on relu == id
                out[idx] = res;
            }
        }
    }
}

// Fallback (R6 kernel, proven): in-loop conversion, no workspace needed.
__global__ void resfc_fallback_kernel(
    const float* X, const float* W,
    const float* Bp, const float* Br,
    float* out)
{
    __shared__ __align__(16) unsigned int sA[128 * 16];
    __shared__ __align__(16) unsigned int sB[128 * 16];

    const int t    = threadIdx.x;
    const int lane = t & 63;
    const int wave = t >> 6;
    const int quad = lane >> 4;
    const int l16  = lane & 15;
    const int wm   = wave >> 1;
    const int wn   = wave & 1;

    const int bm0 = blockIdx.y * 128;
    const int bn0 = blockIdx.x * 128;

    const float* gA[4];
    const float* gB[4];
    int ldsIdx[4];
    for (int c = 0; c < 4; c++) {
        const int ch   = t + c * 256;
        const int row  = ch >> 3;
        const int col4 = ch & 7;
        gA[c] = X + (size_t)(bm0 + row) * NDIM + col4 * 4;
        gB[c] = W + (size_t)(bn0 + row) * NDIM + col4 * 4;
        ldsIdx[c] = row * 16 + col4 * 2;
    }

    const bf16x8* pa = (const bf16x8*)sA + (wm * 64 + l16) * 4 + quad;
    const bf16x8* pb = (const bf16x8*)sB + (wn * 64 + l16) * 4 + quad;

    f32x4 acc[4][4];
    for (int i = 0; i < 4; i++)
        for (int j = 0; j < 4; j++)
            for (int r = 0; r < 4; r++)
                acc[i][j][r] = 0.0f;

    for (int k0 = 0; k0 < NDIM; k0 += 32) {
        float4 va[4], vb[4];
        for (int c = 0; c < 4; c++) {
            va[c] = *(const float4*)(gA[c] + k0);
            vb[c] = *(const float4*)(gB[c] + k0);
        }
        __syncthreads();
        for (int c = 0; c < 4; c++) {
            uint2 ua, ub;
            ua.x = pack_bf2(va[c].x, va[c].y);
            ua.y = pack_bf2(va[c].z, va[c].w);
            ub.x = pack_bf2(vb[c].x, vb[c].y);
            ub.y = pack_bf2(vb[c].z, vb[c].w);
            *(uint2*)(sA + ldsIdx[c]) = ua;
            *(uint2*)(sB + ldsIdx[c]) = ub;
        }
        __syncthreads();

        bf16x8 af[4], bfr[4];
        for (int mt = 0; mt < 4; mt++) af[mt]  = pa[mt * 64];
        for (int nt = 0; nt < 4; nt++) bfr[nt] = pb[nt * 64];

        for (int mt = 0; mt < 4; mt++)
            for (int nt = 0; nt < 4; nt++)
                acc[mt][nt] = __builtin_amdgcn_mfma_f32_16x16x32_bf16(
                    af[mt], bfr[nt], acc[mt][nt], 0, 0, 0);
    }

    const float one_m_beta = 1.0f - Bp[0];
    for (int nt = 0; nt < 4; nt++) {
        const int n = bn0 + wn * 64 + nt * 16 + l16;
        const float br = Br[n];
        for (int mt = 0; mt < 4; mt++) {
            const int mbase = bm0 + wm * 64 + mt * 16 + quad * 4;
            for (int r = 0; r < 4; r++) {
                const size_t idx = (size_t)(mbase + r) * NDIM + n;
                float v = acc[mt][nt][r] + one_m_beta;
                if (v < 0.0f) v = 0.0f;
                float res = 1.0f - br + X[idx] + v;
                if (res < 0.0f) res = 0.0f;
                out[idx] = res;
            }
        }
    }
}

extern "C" void kernel_launch(void* const* d_in, const int* in_sizes, int n_in,
                              void* d_out, int out_size, void* d_ws, size_t ws_size,
                              hipStream_t stream) {
    (void)in_sizes; (void)n_in; (void)out_size;

    const float* X  = (const float*)d_in[0];
    const float* W  = (const float*)d_in[1];
    const float* Bp = (const float*)d_in[2];
    const float* Br = (const float*)d_in[3];
    float* out      = (float*)d_out;

    const size_t elems   = (size_t)NDIM * NDIM;          // 16.7M per matrix
    const size_t bf_need = elems * 2 * 2;                // Xbf + Wbf, 2 B each

    if (ws_size >= bf_need) {
        unsigned int* Xbf = (unsigned int*)d_ws;
        unsigned int* Wbf = (unsigned int*)d_ws + elems / 2;   // uint = 2 bf16

        hipLaunchKernelGGL(convert_f32_bf16_kernel, dim3(16384), dim3(256),
                           0, stream, X, Xbf, W, Wbf);
        hipLaunchKernelGGL(ResFCEventuallyLayer_82205674045459_kernel,
                           dim3(512), dim3(256), 0, stream, Xbf, Wbf, X, Bp, Br, out);
    } else {
        hipLaunchKernelGGL(resfc_fallback_kernel,
                           dim3(NDIM / 128, NDIM / 128), dim3(256), 0, stream,
                           X, W, Bp, Br, out);
    }
}